// Round 11
// baseline (1291.346 us; speedup 1.0000x reference)
//
#include <hip/hip_runtime.h>
#include <math.h>

// Problem constants (from the reference file)
#define NN   20000
#define EE   320000
#define DD   256
#define HH   8
#define CC   32
#define DFFN 1024
#define LLAY 4
#define INDIM 64

typedef _Float16 f16;
typedef __attribute__((ext_vector_type(8))) _Float16 f16x8;
typedef __attribute__((ext_vector_type(4))) _Float16 f16x4;
typedef __attribute__((ext_vector_type(4))) float    f32x4;

// ---------------------------------------------------------------------------
// f16-MFMA GEMM: out[M,Nout] = op( A[M,K](f16) @ W[K,Nout](chunked f16) + bias )
// BN=128, BK=32; 256 thr = 4 waves (2x2). mfma_f32_16x16x32_f16.
//   BM=128: wave tile 64x64 (4x4 frags, 16 mfma/K-step) — wide outputs (1256 blk)
//   BM=64 : wave tile 32x64 (2x4 frags)                 — Nout=256 outputs (626 blk)
// W chunked: Wt[c][n][j] = W[c*8+j][n] (granule = 8 consecutive k for col n).
// LDS: Af[c][row][8], Bf[c][col][8]; staged via global_load_lds width 16:
// per-lane GLOBAL src + wave-uniform LDS base + lane*16 (guide §5; m97 ladder).
// Two barriers per K-step: (1) after issue -> vmcnt drained, tiles visible;
// (2) after MFMA -> all waves done reading before next overwrite.
// MODE: 0 = f32 store | 1 = relu + f16 store | 2 = f32 residual add + f16 copy
//     | 3 = f16 store
// FUSED: A is concat [A0|A1|A2], each [M,256] f16 (K must be 768)
// ---------------------------------------------------------------------------
template<int MODE, int BM, bool FUSED>
__global__ __launch_bounds__(256)
void hgemm_k(const f16* __restrict__ A0, const f16* __restrict__ A1,
             const f16* __restrict__ A2, const f16* __restrict__ Wt,
             const float* __restrict__ bias, float* __restrict__ outF,
             f16* __restrict__ outH, f16* __restrict__ outH2,
             int M, int K, int Nout)
{
    constexpr int MF = BM / 32;        // m-fragments per wave
    __shared__ f16 Af[4 * BM * 8];     // 4 or 8 KB
    __shared__ f16 Bf[4 * 128 * 8];    // 8 KB

    const int tid  = threadIdx.x;
    const int wid  = tid >> 6;
    const int lane = tid & 63;
    const int g    = lane >> 4;        // k-subchunk 0..3
    const int ln   = lane & 15;
    const int WR   = wid >> 1;         // wave row 0..1
    const int WC   = wid & 1;          // wave col 0..1
    const int bm   = blockIdx.x * BM;
    const int bn   = blockIdx.y * 128;

    f32x4 acc[MF][4];
#pragma unroll
    for (int m = 0; m < MF; ++m)
#pragma unroll
        for (int n = 0; n < 4; ++n) acc[m][n] = (f32x4){0.f, 0.f, 0.f, 0.f};

    for (int k0 = 0; k0 < K; k0 += 32) {
        // ---- stage A tile: Af[c][r][8] <- A[bm+r][k0+8c .. +7] ----
        if (BM == 128) {
#pragma unroll
            for (int t = 0; t < 2; ++t) {
                const int ia = wid + t * 4;       // 0..7
                const int c = ia & 3, rb = ia >> 2;
                int grow = bm + rb * 64 + lane;
                grow = grow < M ? grow : (M - 1);  // clamp; epilogue discards
                const f16* gsrc;
                if (FUSED) {
                    const int kg  = k0 + c * 8;
                    const int sel = kg >> 8;
                    const f16* Asrc = (sel == 0) ? A0 : ((sel == 1) ? A1 : A2);
                    gsrc = Asrc + (size_t)grow * 256 + (kg & 255);
                } else {
                    gsrc = A0 + (size_t)grow * K + k0 + c * 8;
                }
                __builtin_amdgcn_global_load_lds(
                    (const __attribute__((address_space(1))) void*)gsrc,
                    (__attribute__((address_space(3))) void*)&Af[(c * 128 + rb * 64) * 8],
                    16, 0, 0);
            }
        } else {
            const int c = wid;                    // one instr per wave
            int grow = bm + lane;
            grow = grow < M ? grow : (M - 1);
            const f16* gsrc;
            if (FUSED) {
                const int kg  = k0 + c * 8;
                const int sel = kg >> 8;
                const f16* Asrc = (sel == 0) ? A0 : ((sel == 1) ? A1 : A2);
                gsrc = Asrc + (size_t)grow * 256 + (kg & 255);
            } else {
                gsrc = A0 + (size_t)grow * K + k0 + c * 8;
            }
            __builtin_amdgcn_global_load_lds(
                (const __attribute__((address_space(1))) void*)gsrc,
                (__attribute__((address_space(3))) void*)&Af[(c * 64) * 8],
                16, 0, 0);
        }
        // ---- stage B tile: Bf[c][col][8] <- Wt[(k0>>3)+c][bn+col][0..7] ----
#pragma unroll
        for (int t = 0; t < 2; ++t) {
            const int ib = wid + t * 4;           // 0..7
            const int c = ib & 3, cb = ib >> 2;
            const f16* gsrc = Wt + ((size_t)((k0 >> 3) + c) * Nout + bn + cb * 64 + lane) * 8;
            __builtin_amdgcn_global_load_lds(
                (const __attribute__((address_space(1))) void*)gsrc,
                (__attribute__((address_space(3))) void*)&Bf[(c * 128 + cb * 64) * 8],
                16, 0, 0);
        }
        __syncthreads();   // vmcnt drained -> tiles complete & visible

        f16x8 af[MF], bf[4];
#pragma unroll
        for (int m = 0; m < MF; ++m)
            af[m] = *(const f16x8*)&Af[(g * BM + WR * (BM / 2) + m * 16 + ln) * 8];
#pragma unroll
        for (int n = 0; n < 4; ++n)
            bf[n] = *(const f16x8*)&Bf[(g * 128 + WC * 64 + n * 16 + ln) * 8];
#pragma unroll
        for (int m = 0; m < MF; ++m)
#pragma unroll
            for (int n = 0; n < 4; ++n)
                acc[m][n] = __builtin_amdgcn_mfma_f32_16x16x32_f16(af[m], bf[n], acc[m][n], 0, 0, 0);
        __syncthreads();   // all waves done reading before next stage overwrites
    }

    // ---- epilogue: C/D map col=ln, row=g*4+reg per 16x16 fragment ----
    float bvv[4];
#pragma unroll
    for (int n = 0; n < 4; ++n) bvv[n] = bias[bn + WC * 64 + n * 16 + ln];

#pragma unroll
    for (int m = 0; m < MF; ++m) {
        const int rbase = bm + WR * (BM / 2) + m * 16 + g * 4;
#pragma unroll
        for (int reg = 0; reg < 4; ++reg) {
            const int row = rbase + reg;
            if (row >= M) continue;
#pragma unroll
            for (int n = 0; n < 4; ++n) {
                const int col = bn + WC * 64 + n * 16 + ln;
                float v = acc[m][n][reg] + bvv[n];
                const size_t idx = (size_t)row * Nout + col;
                if (MODE == 0) {
                    outF[idx] = v;
                } else if (MODE == 1) {
                    outH[idx] = (f16)fmaxf(v, 0.f);
                } else if (MODE == 2) {
                    const float nv = outF[idx] + v;
                    outF[idx] = nv;
                    outH2[idx] = (f16)nv;
                } else {
                    outH[idx] = (f16)v;
                }
            }
        }
    }
}

// ---------------------------------------------------------------------------
// Weight conversion: W [K,N] f32 -> Wt chunked f16 [K/8][N][8]; grid.y = layer
// (grid.y MUST be 1 for unstacked weights — Wfus is [768,256] with NO L dim;
//  the round-4/5 crash was a 2.25MB OOB read from grid.y=LLAY on Wfus).
// ---------------------------------------------------------------------------
__global__ __launch_bounds__(256)
void cvtW_k(const float* __restrict__ W, f16* __restrict__ Wt, int K, int N)
{
    const size_t lo  = (size_t)blockIdx.y * K * N;
    const int    idx = blockIdx.x * 256 + threadIdx.x;   // over K*N
    const int    k   = idx / N;
    const int    n   = idx - k * N;
    Wt[lo + ((size_t)(k >> 3) * N + n) * 8 + (k & 7)] = (f16)W[lo + idx];
}

// Pack Wq|Wk|Wv|Wskip ([L,256,256] each) into chunked f16 [32][1024][8] per
// layer + f32 bias [1024]. grid.y = layer.
__global__ __launch_bounds__(256)
void cvtW4_k(const float* __restrict__ Wq, const float* __restrict__ Wk,
             const float* __restrict__ Wv, const float* __restrict__ Ws,
             const float* __restrict__ bq, const float* __restrict__ bk,
             const float* __restrict__ bv, const float* __restrict__ bs,
             f16* __restrict__ Wt, float* __restrict__ bout)
{
    const int l   = blockIdx.y;
    const int idx = blockIdx.x * 256 + threadIdx.x;   // over 256*1024
    const int k   = idx >> 10;
    const int n   = idx & 1023;
    const int m   = n >> 8;          // 0=q 1=k 2=v 3=skip
    const int c   = n & 255;
    const float* src = (m == 0) ? Wq : (m == 1) ? Wk : (m == 2) ? Wv : Ws;
    const float  v   = src[(size_t)l * 65536 + k * 256 + c];
    Wt[(size_t)l * 262144 + ((size_t)(k >> 3) * 1024 + n) * 8 + (k & 7)] = (f16)v;
    if (k == 0) {
        const float* bsrc = (m == 0) ? bq : (m == 1) ? bk : (m == 2) ? bv : bs;
        bout[l * 1024 + n] = bsrc[l * 256 + c];
    }
}

// Elementwise f32 -> f16. n multiple of 4.
__global__ __launch_bounds__(256)
void cvt_act_k(const float* __restrict__ in, f16* __restrict__ out, int n)
{
    const int i = (blockIdx.x * 256 + threadIdx.x) * 4;
    if (i < n) {
        const float4 v = *(const float4*)&in[i];
        f16x4 o = {(f16)v.x, (f16)v.y, (f16)v.z, (f16)v.w};
        *(f16x4*)&out[i] = o;
    }
}

// ---------------------------------------------------------------------------
// LayerNorm over D=256, f32 in, f16 or f32 out. One wave per row.
// ---------------------------------------------------------------------------
template<typename T>
__global__ __launch_bounds__(256)
void ln_k(const float* __restrict__ in, const float* __restrict__ g,
          const float* __restrict__ b, T* __restrict__ out, int M)
{
    const int wave = threadIdx.x >> 6;
    const int lane = threadIdx.x & 63;
    const int row  = blockIdx.x * 4 + wave;
    if (row >= M) return;

    const float4 v = *(const float4*)&in[(size_t)row * DD + lane * 4];
    float s = v.x + v.y + v.z + v.w;
#pragma unroll
    for (int off = 32; off; off >>= 1) s += __shfl_xor(s, off, 64);
    const float mu = s * (1.f / 256.f);

    const float dx = v.x - mu, dy = v.y - mu, dz = v.z - mu, dw = v.w - mu;
    float q = dx*dx + dy*dy + dz*dz + dw*dw;
#pragma unroll
    for (int off = 32; off; off >>= 1) q += __shfl_xor(q, off, 64);
    const float rs = rsqrtf(q * (1.f / 256.f) + 1e-5f);

    const float4 gv = *(const float4*)&g[lane * 4];
    const float4 bv = *(const float4*)&b[lane * 4];
    const float ox = dx * rs * gv.x + bv.x;
    const float oy = dy * rs * gv.y + bv.y;
    const float oz = dz * rs * gv.z + bv.z;
    const float ow = dw * rs * gv.w + bv.w;
    if constexpr (sizeof(T) == 2) {
        f16x4 o = {(f16)ox, (f16)oy, (f16)oz, (f16)ow};
        *(f16x4*)&out[(size_t)row * DD + lane * 4] = o;
    } else {
        float4 o = {ox, oy, oz, ow};
        *(float4*)&out[(size_t)row * DD + lane * 4] = o;
    }
}

// ---------------------------------------------------------------------------
// CSR build [round-3 proven]
// ---------------------------------------------------------------------------
__global__ void hist_k(const int* __restrict__ dst, int* __restrict__ cnt)
{
    const int e = blockIdx.x * blockDim.x + threadIdx.x;
    if (e < EE) atomicAdd(&cnt[dst[e]], 1);
}

__global__ __launch_bounds__(256)
void scan_k(const int* __restrict__ cnt, int* __restrict__ row_ptr,
            int* __restrict__ cursor)
{
    __shared__ int sums[256];
    const int t  = threadIdx.x;
    const int CH = (NN + 255) / 256;       // 79
    const int s0 = t * CH;
    const int s1 = min(s0 + CH, NN);

    int s = 0;
    for (int i = s0; i < s1; ++i) s += cnt[i];
    sums[t] = s;
    __syncthreads();
    for (int off = 1; off < 256; off <<= 1) {
        const int v = (t >= off) ? sums[t - off] : 0;
        __syncthreads();
        sums[t] += v;
        __syncthreads();
    }
    int run = (t == 0) ? 0 : sums[t - 1];
    for (int i = s0; i < s1; ++i) {
        row_ptr[i] = run;
        cursor[i]  = run;
        run += cnt[i];
    }
    if (t == 255) row_ptr[NN] = run;       // == EE
}

__global__ void scatter_k(const int* __restrict__ dst, int* __restrict__ cursor,
                          int* __restrict__ eids)
{
    const int e = blockIdx.x * blockDim.x + threadIdx.x;
    if (e < EE) {
        const int idx = atomicAdd(&cursor[dst[e]], 1);
        eids[idx] = e;
    }
}

// ---------------------------------------------------------------------------
// Fused edge attention, qkvs f16 [N,1024] = [q|k|v|skip]. [round-9 proven]
// One block per dst node; channel = tid; online softmax per 32-lane head;
// 2 edges/iter. Epilogue: x[i] += msg + skip[i].
// ---------------------------------------------------------------------------
__global__ __launch_bounds__(256)
void edge_attn_k(const f16* __restrict__ qkvs, const float* __restrict__ edge_attr,
                 const float* __restrict__ Wel, const int* __restrict__ row_ptr,
                 const int* __restrict__ eids, const int* __restrict__ srcarr,
                 float* __restrict__ x)
{
    const int i   = blockIdx.x;
    const int tid = threadIdx.x;

    float wc[16];
#pragma unroll
    for (int t = 0; t < 16; ++t) wc[t] = Wel[t * DD + tid];   // We[:, ch]

    const float qv = (float)qkvs[(size_t)i * 1024 + tid] * 0.17677669529663687f;

    float m = -INFINITY, s = 0.f, acc = 0.f;
    const int jbeg = row_ptr[i];
    const int jend = row_ptr[i + 1];

    int j = jbeg;
    for (; j + 1 < jend; j += 2) {
        const int e0 = eids[j],     e1 = eids[j + 1];
        const int s0 = srcarr[e0],  s1 = srcarr[e1];

        const float4* ea0p = (const float4*)(edge_attr + (size_t)e0 * 16);
        const float4* ea1p = (const float4*)(edge_attr + (size_t)e1 * 16);
        const float4 a00 = ea0p[0], a01 = ea0p[1], a02 = ea0p[2], a03 = ea0p[3];
        const float4 a10 = ea1p[0], a11 = ea1p[1], a12 = ea1p[2], a13 = ea1p[3];
        float kv0 = (float)qkvs[(size_t)s0 * 1024 + 256 + tid];
        float vv0 = (float)qkvs[(size_t)s0 * 1024 + 512 + tid];
        float kv1 = (float)qkvs[(size_t)s1 * 1024 + 256 + tid];
        float vv1 = (float)qkvs[(size_t)s1 * 1024 + 512 + tid];

        const float ev0 =
            a00.x*wc[0]  + a00.y*wc[1]  + a00.z*wc[2]  + a00.w*wc[3]  +
            a01.x*wc[4]  + a01.y*wc[5]  + a01.z*wc[6]  + a01.w*wc[7]  +
            a02.x*wc[8]  + a02.y*wc[9]  + a02.z*wc[10] + a02.w*wc[11] +
            a03.x*wc[12] + a03.y*wc[13] + a03.z*wc[14] + a03.w*wc[15];
        const float ev1 =
            a10.x*wc[0]  + a10.y*wc[1]  + a10.z*wc[2]  + a10.w*wc[3]  +
            a11.x*wc[4]  + a11.y*wc[5]  + a11.z*wc[6]  + a11.w*wc[7]  +
            a12.x*wc[8]  + a12.y*wc[9]  + a12.z*wc[10] + a12.w*wc[11] +
            a13.x*wc[12] + a13.y*wc[13] + a13.z*wc[14] + a13.w*wc[15];
        kv0 += ev0; vv0 += ev0;
        kv1 += ev1; vv1 += ev1;

        float d0 = qv * kv0;
        float d1 = qv * kv1;
#pragma unroll
        for (int off = 16; off; off >>= 1) {
            d0 += __shfl_xor(d0, off, 32);
            d1 += __shfl_xor(d1, off, 32);
        }

        const float mn   = fmaxf(m, fmaxf(d0, d1));
        const float corr = __expf(m - mn);
        const float p0   = __expf(d0 - mn);
        const float p1   = __expf(d1 - mn);
        s   = s * corr + p0 + p1;
        acc = acc * corr + p0 * vv0 + p1 * vv1;
        m   = mn;
    }
    if (j < jend) {
        const int e  = eids[j];
        const int sj = srcarr[e];
        const float4* eap = (const float4*)(edge_attr + (size_t)e * 16);
        const float4 ea0 = eap[0], ea1 = eap[1], ea2 = eap[2], ea3 = eap[3];
        float kv = (float)qkvs[(size_t)sj * 1024 + 256 + tid];
        float vv = (float)qkvs[(size_t)sj * 1024 + 512 + tid];
        const float ev =
            ea0.x*wc[0]  + ea0.y*wc[1]  + ea0.z*wc[2]  + ea0.w*wc[3]  +
            ea1.x*wc[4]  + ea1.y*wc[5]  + ea1.z*wc[6]  + ea1.w*wc[7]  +
            ea2.x*wc[8]  + ea2.y*wc[9]  + ea2.z*wc[10] + ea2.w*wc[11] +
            ea3.x*wc[12] + ea3.y*wc[13] + ea3.z*wc[14] + ea3.w*wc[15];
        kv += ev; vv += ev;
        float a = qv * kv;
#pragma unroll
        for (int off = 16; off; off >>= 1) a += __shfl_xor(a, off, 32);
        const float mn   = fmaxf(m, a);
        const float corr = __expf(m - mn);
        const float p    = __expf(a - mn);
        s   = s * corr + p;
        acc = acc * corr + p * vv;
        m   = mn;
    }

    const float msg = acc / (s + 1e-16f);
    const size_t o  = (size_t)i * DD + tid;
    x[o] += msg + (float)qkvs[(size_t)i * 1024 + 768 + tid];
}

// ---------------------------------------------------------------------------
// Launcher
// ---------------------------------------------------------------------------
extern "C" void kernel_launch(void* const* d_in, const int* in_sizes, int n_in,
                              void* d_out, int out_size, void* d_ws, size_t ws_size,
                              hipStream_t stream)
{
    const float* input = (const float*)d_in[0];
    const float* nemb  = (const float*)d_in[1];
    const float* eattr = (const float*)d_in[2];
    const int*   eidx  = (const int*)d_in[3];
    const float* Win   = (const float*)d_in[4];
    const float* b_in  = (const float*)d_in[5];
    const float* Wemb  = (const float*)d_in[6];
    const float* bemb  = (const float*)d_in[7];
    const float* Wfus  = (const float*)d_in[8];
    const float* bfus  = (const float*)d_in[9];
    const float* Wq    = (const float*)d_in[10];
    const float* bq    = (const float*)d_in[11];
    const float* Wk    = (const float*)d_in[12];
    const float* bk    = (const float*)d_in[13];
    const float* Wv    = (const float*)d_in[14];
    const float* bv    = (const float*)d_in[15];
    const float* We    = (const float*)d_in[16];
    const float* Wskip = (const float*)d_in[17];
    const float* bskip = (const float*)d_in[18];
    const float* n1g   = (const float*)d_in[19];
    const float* n1b   = (const float*)d_in[20];
    const float* W1f   = (const float*)d_in[21];
    const float* b1f   = (const float*)d_in[22];
    const float* W2f   = (const float*)d_in[23];
    const float* b2f   = (const float*)d_in[24];
    const float* n2g   = (const float*)d_in[25];
    const float* n2b   = (const float*)d_in[26];
    const float* fng   = (const float*)d_in[27];
    const float* fnb   = (const float*)d_in[28];

    const int* srcarr = eidx;
    const int* dstarr = eidx + EE;

    // -------- workspace layout (~113 MB) --------
    char* p = (char*)d_ws;
    auto alloc = [&](size_t bytes) { char* r = p; p += (bytes + 255) & ~(size_t)255; return r; };
    const size_t ND = (size_t)NN * DD;
    float* xA      = (float*)alloc(ND * 4);                 // f32 residual stream
    f16*   h_inp   = (f16*)alloc(ND * 2);
    f16*   h_emb   = (f16*)alloc(ND * 2);
    f16*   h_x     = (f16*)alloc(ND * 2);
    f16*   xn_h    = (f16*)alloc(ND * 2);
    f16*   qkvs_h  = (f16*)alloc((size_t)NN * 1024 * 2);    // also FFN mid (sequential use)
    f16*   mid_h   = qkvs_h;
    f16*   h_input = (f16*)alloc((size_t)NN * INDIM * 2);
    f16*   h_nemb  = (f16*)alloc((size_t)NN * INDIM * 2);
    f16*   Wt_in   = (f16*)alloc((size_t)INDIM * DD * 2);
    f16*   Wt_emb  = (f16*)alloc((size_t)INDIM * DD * 2);
    f16*   Wt_fus  = (f16*)alloc((size_t)768 * DD * 2);     // SINGLE layer (no L dim!)
    f16*   Wt_pack = (f16*)alloc((size_t)LLAY * DD * 1024 * 2);
    f16*   Wt_f1   = (f16*)alloc((size_t)LLAY * DD * DFFN * 2);
    f16*   Wt_f2   = (f16*)alloc((size_t)LLAY * DFFN * DD * 2);
    float* bpack   = (float*)alloc((size_t)LLAY * 1024 * 4);
    int*   cnt     = (int*)alloc(NN * 4);
    int*   cursor  = (int*)alloc(NN * 4);
    int*   row_ptr = (int*)alloc((NN + 1) * 4);
    int*   eids    = (int*)alloc(EE * 4);

    const int  lnGrid = (NN + 3) / 4;
    const dim3 gS(313, 2);   // BM=64,  Nout=256  (313*64 = 20032 rows)
    const dim3 gW(157, 8);   // BM=128, Nout=1024 (157*128 = 20096 rows)

    // -------- weight & activation conversion --------
    hipMemsetAsync(cnt, 0, NN * sizeof(int), stream);
    cvtW_k<<<dim3(INDIM * DD / 256, 1), 256, 0, stream>>>(Win,  Wt_in,  INDIM, DD);
    cvtW_k<<<dim3(INDIM * DD / 256, 1), 256, 0, stream>>>(Wemb, Wt_emb, INDIM, DD);
    cvtW_k<<<dim3(768 * DD / 256,  1), 256, 0, stream>>>(Wfus, Wt_fus, 768, DD);   // grid.y=1: Wfus SHARED
    cvtW_k<<<dim3(DD * DFFN / 256, LLAY), 256, 0, stream>>>(W1f,  Wt_f1,  DD, DFFN);
    cvtW_k<<<dim3(DFFN * DD / 256, LLAY), 256, 0, stream>>>(W2f,  Wt_f2,  DFFN, DD);
    cvtW4_k<<<dim3(DD * 1024 / 256, LLAY), 256, 0, stream>>>(Wq, Wk, Wv, Wskip,
                                                             bq, bk, bv, bskip, Wt_pack, bpack);
    cvt_act_k<<<NN * INDIM / 4 / 256, 256, 0, stream>>>(input, h_input, NN * INDIM);
    cvt_act_k<<<NN * INDIM / 4 / 256, 256, 0, stream>>>(nemb,  h_nemb,  NN * INDIM);

    // input projections -> f16 [N,256]
    hgemm_k<3,64,false><<<gS, 256, 0, stream>>>(h_input, nullptr, nullptr, Wt_in,  b_in,
                                                nullptr, h_inp, nullptr, NN, INDIM, DD);
    hgemm_k<3,64,false><<<gS, 256, 0, stream>>>(h_nemb,  nullptr, nullptr, Wt_emb, bemb,
                                                nullptr, h_emb, nullptr, NN, INDIM, DD);
    // CSR build
    hist_k<<<EE / 256, 256, 0, stream>>>(dstarr, cnt);
    scan_k<<<1, 256, 0, stream>>>(cnt, row_ptr, cursor);
    scatter_k<<<EE / 256, 256, 0, stream>>>(dstarr, cursor, eids);

    for (int l = 0; l < LLAY; ++l) {
        const f16* hx_l = (l == 0) ? h_emb : h_x;

        // x = concat(x, inp_proj, emb_proj) @ Wfus + bfus -> xA (f32); Wt_fus shared
        hgemm_k<0,64,true><<<gS, 256, 0, stream>>>(hx_l, h_inp, h_emb,
            Wt_fus, bfus, xA, nullptr, nullptr, NN, 768, DD);
        // prenorm 1 -> f16
        ln_k<f16><<<lnGrid, 256, 0, stream>>>(xA, n1g + l * DD, n1b + l * DD, xn_h, NN);
        // q|k|v|skip in one GEMM -> f16 [N,1024]
        hgemm_k<3,128,false><<<gW, 256, 0, stream>>>(xn_h, nullptr, nullptr,
            Wt_pack + (size_t)l * DD * 1024, bpack + l * 1024, nullptr, qkvs_h, nullptr, NN, DD, 1024);
        // fused edge attention + skip + residual: xA += msg + skip
        edge_attn_k<<<NN, 256, 0, stream>>>(qkvs_h, eattr, We + (size_t)l * 16 * DD,
                                            row_ptr, eids, srcarr, xA);
        // prenorm 2 -> f16
        ln_k<f16><<<lnGrid, 256, 0, stream>>>(xA, n2g + l * DD, n2b + l * DD, xn_h, NN);
        // FFN: relu(xn @ W1f + b1f) -> f16 mid; xA += mid @ W2f + b2f (also emit h_x f16)
        hgemm_k<1,128,false><<<gW, 256, 0, stream>>>(xn_h, nullptr, nullptr,
            Wt_f1 + (size_t)l * DD * DFFN, b1f + l * DFFN, nullptr, mid_h, nullptr, NN, DD, DFFN);
        hgemm_k<2,64,false><<<gS, 256, 0, stream>>>(mid_h, nullptr, nullptr,
            Wt_f2 + (size_t)l * DFFN * DD, b2f + l * DD, xA, nullptr, h_x, NN, DFFN, DD);
    }

    // final LN -> d_out (f32)
    ln_k<float><<<lnGrid, 256, 0, stream>>>(xA, fng, fnb, (float*)d_out, NN);
}

// Round 12
// 1276.629 us; speedup vs baseline: 1.0115x; 1.0115x over previous
//
#include <hip/hip_runtime.h>
#include <math.h>

// Problem constants (from the reference file)
#define NN   20000
#define EE   320000
#define DD   256
#define HH   8
#define CC   32
#define DFFN 1024
#define LLAY 4
#define INDIM 64

typedef _Float16 f16;
typedef __attribute__((ext_vector_type(8))) _Float16 f16x8;
typedef __attribute__((ext_vector_type(4))) _Float16 f16x4;
typedef __attribute__((ext_vector_type(4))) float    f32x4;

// ---------------------------------------------------------------------------
// f16-MFMA GEMM [round-9 proven form — reg-staged, BM=64]:
//   out[M,Nout] = op( A[M,K](f16) @ W[K,Nout](chunked f16) + bias )
// BM=64, BN=128, BK=32; 256 thr = 4 waves in 2x2 grid; wave tile 32x64.
// W chunked: Wt[c][n][j] = W[c*8+j][n].
// MODE: 0 = f32 store | 1 = relu + f16 store | 2 = f32 residual add + f16 copy
//     | 3 = f16 store
// FUSED: A is concat [A0|A1|A2], each [M,256] f16 (K must be 768)
// ---------------------------------------------------------------------------
template<int MODE, bool FUSED>
__global__ __launch_bounds__(256)
void hgemm_k(const f16* __restrict__ A0, const f16* __restrict__ A1,
             const f16* __restrict__ A2, const f16* __restrict__ Wt,
             const float* __restrict__ bias, float* __restrict__ outF,
             f16* __restrict__ outH, f16* __restrict__ outH2,
             int M, int K, int Nout)
{
    __shared__ f16 Af[4 * 64 * 8];     // 4 KB
    __shared__ f16 Bf[4 * 128 * 8];    // 8 KB

    const int tid  = threadIdx.x;
    const int wid  = tid >> 6;
    const int lane = tid & 63;
    const int g    = lane >> 4;        // k-subchunk 0..3
    const int ln   = lane & 15;
    const int WR   = wid >> 1;         // wave row 0..1 (32 rows each)
    const int WC   = wid & 1;          // wave col 0..1 (64 cols each)
    const int bm   = blockIdx.x * 64;
    const int bn   = blockIdx.y * 128;

    f32x4 acc[2][4];
#pragma unroll
    for (int m = 0; m < 2; ++m)
#pragma unroll
        for (int n = 0; n < 4; ++n) acc[m][n] = (f32x4){0.f, 0.f, 0.f, 0.f};

    // A staging map: thread -> granule (c = tid&3, r = tid>>2)
    const int ar = tid >> 2;           // 0..63
    const int ac = tid & 3;            // 0..3

    for (int k0 = 0; k0 < K; k0 += 32) {
        // ---- A granule: A[bm+ar][k0+8*ac .. +7] ----
        f16x8 av = {};
        {
            const int grow = bm + ar;
            if (grow < M) {
                const f16* gsrc;
                if (FUSED) {
                    const int kg  = k0 + ac * 8;
                    const int sel = kg >> 8;
                    const f16* Asrc = (sel == 0) ? A0 : ((sel == 1) ? A1 : A2);
                    gsrc = Asrc + (size_t)grow * 256 + (kg & 255);
                } else {
                    gsrc = A0 + (size_t)grow * K + k0 + ac * 8;
                }
                av = *(const f16x8*)gsrc;
            }
        }
        // ---- B granules (2/thread): granule (c = s>>7, col = s&127) ----
        f16x8 bv0, bv1;
        {
            const int s0 = tid;              // c = tid>>7 (0..1), col = tid&127
            const int s1 = tid + 256;        // c = 2..3
            bv0 = *(const f16x8*)(Wt + ((size_t)((k0 >> 3) + (s0 >> 7)) * Nout + bn + (s0 & 127)) * 8);
            bv1 = *(const f16x8*)(Wt + ((size_t)((k0 >> 3) + (s1 >> 7)) * Nout + bn + (s1 & 127)) * 8);
        }

        __syncthreads();                     // previous iter's reads done
        *(f16x8*)&Af[(ac * 64 + ar) * 8] = av;
        *(f16x8*)&Bf[(size_t)tid * 8]         = bv0;
        *(f16x8*)&Bf[(size_t)(tid + 256) * 8] = bv1;
        __syncthreads();                     // tiles visible

        f16x8 af[2], bf[4];
#pragma unroll
        for (int m = 0; m < 2; ++m)
            af[m] = *(const f16x8*)&Af[(g * 64 + WR * 32 + m * 16 + ln) * 8];
#pragma unroll
        for (int n = 0; n < 4; ++n)
            bf[n] = *(const f16x8*)&Bf[(g * 128 + WC * 64 + n * 16 + ln) * 8];
#pragma unroll
        for (int m = 0; m < 2; ++m)
#pragma unroll
            for (int n = 0; n < 4; ++n)
                acc[m][n] = __builtin_amdgcn_mfma_f32_16x16x32_f16(af[m], bf[n], acc[m][n], 0, 0, 0);
    }

    // ---- epilogue: C/D map col=ln, row=g*4+reg per 16x16 fragment ----
    float bvv[4];
#pragma unroll
    for (int n = 0; n < 4; ++n) bvv[n] = bias[bn + WC * 64 + n * 16 + ln];

#pragma unroll
    for (int m = 0; m < 2; ++m) {
        const int rbase = bm + WR * 32 + m * 16 + g * 4;
#pragma unroll
        for (int reg = 0; reg < 4; ++reg) {
            const int row = rbase + reg;
            if (row >= M) continue;
#pragma unroll
            for (int n = 0; n < 4; ++n) {
                const int col = bn + WC * 64 + n * 16 + ln;
                float v = acc[m][n][reg] + bvv[n];
                const size_t idx = (size_t)row * Nout + col;
                if (MODE == 0) {
                    outF[idx] = v;
                } else if (MODE == 1) {
                    outH[idx] = (f16)fmaxf(v, 0.f);
                } else if (MODE == 2) {
                    const float nv = outF[idx] + v;
                    outF[idx] = nv;
                    outH2[idx] = (f16)nv;
                } else {
                    outH[idx] = (f16)v;
                }
            }
        }
    }
}

// ---------------------------------------------------------------------------
// Weight conversion: W [K,N] f32 -> Wt chunked f16 [K/8][N][8]; grid.y = layer
// (grid.y MUST be 1 for unstacked weights — Wfus is [768,256] with NO L dim;
//  the round-4/5 crash was a 2.25MB OOB read from grid.y=LLAY on Wfus).
// ---------------------------------------------------------------------------
__global__ __launch_bounds__(256)
void cvtW_k(const float* __restrict__ W, f16* __restrict__ Wt, int K, int N)
{
    const size_t lo  = (size_t)blockIdx.y * K * N;
    const int    idx = blockIdx.x * 256 + threadIdx.x;   // over K*N
    const int    k   = idx / N;
    const int    n   = idx - k * N;
    Wt[lo + ((size_t)(k >> 3) * N + n) * 8 + (k & 7)] = (f16)W[lo + idx];
}

// Pack Wq|Wk|Wv|Wskip ([L,256,256] each) into chunked f16 [32][1024][8] per
// layer + f32 bias [1024]. grid.y = layer.
__global__ __launch_bounds__(256)
void cvtW4_k(const float* __restrict__ Wq, const float* __restrict__ Wk,
             const float* __restrict__ Wv, const float* __restrict__ Ws,
             const float* __restrict__ bq, const float* __restrict__ bk,
             const float* __restrict__ bv, const float* __restrict__ bs,
             f16* __restrict__ Wt, float* __restrict__ bout)
{
    const int l   = blockIdx.y;
    const int idx = blockIdx.x * 256 + threadIdx.x;   // over 256*1024
    const int k   = idx >> 10;
    const int n   = idx & 1023;
    const int m   = n >> 8;          // 0=q 1=k 2=v 3=skip
    const int c   = n & 255;
    const float* src = (m == 0) ? Wq : (m == 1) ? Wk : (m == 2) ? Wv : Ws;
    const float  v   = src[(size_t)l * 65536 + k * 256 + c];
    Wt[(size_t)l * 262144 + ((size_t)(k >> 3) * 1024 + n) * 8 + (k & 7)] = (f16)v;
    if (k == 0) {
        const float* bsrc = (m == 0) ? bq : (m == 1) ? bk : (m == 2) ? bv : bs;
        bout[l * 1024 + n] = bsrc[l * 256 + c];
    }
}

// Elementwise f32 -> f16. n multiple of 4.
__global__ __launch_bounds__(256)
void cvt_act_k(const float* __restrict__ in, f16* __restrict__ out, int n)
{
    const int i = (blockIdx.x * 256 + threadIdx.x) * 4;
    if (i < n) {
        const float4 v = *(const float4*)&in[i];
        f16x4 o = {(f16)v.x, (f16)v.y, (f16)v.z, (f16)v.w};
        *(f16x4*)&out[i] = o;
    }
}

// ---------------------------------------------------------------------------
// LayerNorm over D=256, f32 in, f16 or f32 out. One wave per row.
// ---------------------------------------------------------------------------
template<typename T>
__global__ __launch_bounds__(256)
void ln_k(const float* __restrict__ in, const float* __restrict__ g,
          const float* __restrict__ b, T* __restrict__ out, int M)
{
    const int wave = threadIdx.x >> 6;
    const int lane = threadIdx.x & 63;
    const int row  = blockIdx.x * 4 + wave;
    if (row >= M) return;

    const float4 v = *(const float4*)&in[(size_t)row * DD + lane * 4];
    float s = v.x + v.y + v.z + v.w;
#pragma unroll
    for (int off = 32; off; off >>= 1) s += __shfl_xor(s, off, 64);
    const float mu = s * (1.f / 256.f);

    const float dx = v.x - mu, dy = v.y - mu, dz = v.z - mu, dw = v.w - mu;
    float q = dx*dx + dy*dy + dz*dz + dw*dw;
#pragma unroll
    for (int off = 32; off; off >>= 1) q += __shfl_xor(q, off, 64);
    const float rs = rsqrtf(q * (1.f / 256.f) + 1e-5f);

    const float4 gv = *(const float4*)&g[lane * 4];
    const float4 bv = *(const float4*)&b[lane * 4];
    const float ox = dx * rs * gv.x + bv.x;
    const float oy = dy * rs * gv.y + bv.y;
    const float oz = dz * rs * gv.z + bv.z;
    const float ow = dw * rs * gv.w + bv.w;
    if constexpr (sizeof(T) == 2) {
        f16x4 o = {(f16)ox, (f16)oy, (f16)oz, (f16)ow};
        *(f16x4*)&out[(size_t)row * DD + lane * 4] = o;
    } else {
        float4 o = {ox, oy, oz, ow};
        *(float4*)&out[(size_t)row * DD + lane * 4] = o;
    }
}

// ---------------------------------------------------------------------------
// CSR build [round-3 proven]
// ---------------------------------------------------------------------------
__global__ void hist_k(const int* __restrict__ dst, int* __restrict__ cnt)
{
    const int e = blockIdx.x * blockDim.x + threadIdx.x;
    if (e < EE) atomicAdd(&cnt[dst[e]], 1);
}

__global__ __launch_bounds__(256)
void scan_k(const int* __restrict__ cnt, int* __restrict__ row_ptr,
            int* __restrict__ cursor)
{
    __shared__ int sums[256];
    const int t  = threadIdx.x;
    const int CH = (NN + 255) / 256;       // 79
    const int s0 = t * CH;
    const int s1 = min(s0 + CH, NN);

    int s = 0;
    for (int i = s0; i < s1; ++i) s += cnt[i];
    sums[t] = s;
    __syncthreads();
    for (int off = 1; off < 256; off <<= 1) {
        const int v = (t >= off) ? sums[t - off] : 0;
        __syncthreads();
        sums[t] += v;
        __syncthreads();
    }
    int run = (t == 0) ? 0 : sums[t - 1];
    for (int i = s0; i < s1; ++i) {
        row_ptr[i] = run;
        cursor[i]  = run;
        run += cnt[i];
    }
    if (t == 255) row_ptr[NN] = run;       // == EE
}

__global__ void scatter_k(const int* __restrict__ dst, int* __restrict__ cursor,
                          int* __restrict__ eids)
{
    const int e = blockIdx.x * blockDim.x + threadIdx.x;
    if (e < EE) {
        const int idx = atomicAdd(&cursor[dst[e]], 1);
        eids[idx] = e;
    }
}

// ---------------------------------------------------------------------------
// Fused edge attention, ALGEBRAIC RESTRUCTURE:
//   score: q·(k+e) = q·k + ea·qwe   where qwe[h][t] = Σ_c (q_hc/√32)·We[t,h·32+c]
//          (precomputed ONCE per dst block into LDS; per-edge cost = 1 FMA
//           folded into the 32-lane reduce on lanes c<16)
//   value: Σ_j p_j·e_j = (Σ_j p_j·ea_j) @ We — accumulate wea[h][t] online
//          (1 FMA/edge with corr rescale), apply @We once in the epilogue.
// Removes the 16-FMA/thread/edge ev dot + 16 broadcast ea loads/thread/edge.
// qkvs f16 [N,1024] = [q|k|v|skip]. One block per dst node; channel = tid;
// online softmax per 32-lane head; 2 edges/iter. x[i] += msg + skip[i].
// ---------------------------------------------------------------------------
__global__ __launch_bounds__(256)
void edge_attn_k(const f16* __restrict__ qkvs, const float* __restrict__ edge_attr,
                 const float* __restrict__ Wel, const int* __restrict__ row_ptr,
                 const int* __restrict__ eids, const int* __restrict__ srcarr,
                 float* __restrict__ x)
{
    __shared__ float qwe[128];     // [h][t]
    __shared__ float wea_s[128];   // [h][t]

    const int i   = blockIdx.x;
    const int tid = threadIdx.x;
    const int h   = tid >> 5;      // head 0..7
    const int c   = tid & 31;      // channel within head

    // ---- one-time: qwe[h][t] = (q_h/√32) · We[t, h-block] ----
    if (tid < 128) {
        const int hh = tid >> 4, tt = tid & 15;
        const f16*   qrow = qkvs + (size_t)i * 1024 + hh * 32;
        const float* wrow = Wel + tt * 256 + hh * 32;
        const f16x8* q8 = (const f16x8*)qrow;        // 64B-aligned
        float a0 = 0.f;
#pragma unroll
        for (int b = 0; b < 4; ++b) {
            const f16x8 qq = q8[b];
#pragma unroll
            for (int u = 0; u < 8; ++u)
                a0 = fmaf((float)qq[u], wrow[b * 8 + u], a0);
        }
        qwe[tid] = a0 * 0.17677669529663687f;        // 1/sqrt(32)
    }
    const float qv = (float)qkvs[(size_t)i * 1024 + tid] * 0.17677669529663687f;
    __syncthreads();

    const float qwv = (c < 16) ? qwe[h * 16 + c] : 0.f;   // per-thread constant

    float m = -INFINITY, s = 0.f, acc = 0.f, wea = 0.f;
    const int jbeg = row_ptr[i];
    const int jend = row_ptr[i + 1];

    int j = jbeg;
    for (; j + 1 < jend; j += 2) {
        const int e0 = eids[j],     e1 = eids[j + 1];
        const int s0 = srcarr[e0],  s1 = srcarr[e1];

        const float ea0 = edge_attr[(size_t)e0 * 16 + (c & 15)];
        const float ea1 = edge_attr[(size_t)e1 * 16 + (c & 15)];
        const float kv0 = (float)qkvs[(size_t)s0 * 1024 + 256 + tid];
        const float vv0 = (float)qkvs[(size_t)s0 * 1024 + 512 + tid];
        const float kv1 = (float)qkvs[(size_t)s1 * 1024 + 256 + tid];
        const float vv1 = (float)qkvs[(size_t)s1 * 1024 + 512 + tid];

        float d0 = fmaf(qv, kv0, qwv * ea0);   // lanes c>=16: qwv=0
        float d1 = fmaf(qv, kv1, qwv * ea1);
#pragma unroll
        for (int off = 16; off; off >>= 1) {
            d0 += __shfl_xor(d0, off, 32);
            d1 += __shfl_xor(d1, off, 32);
        }

        const float mn   = fmaxf(m, fmaxf(d0, d1));
        const float corr = __expf(m - mn);     // exp(-inf)=0 handles first pair
        const float p0   = __expf(d0 - mn);
        const float p1   = __expf(d1 - mn);
        s   = s   * corr + p0 + p1;
        acc = acc * corr + p0 * vv0 + p1 * vv1;
        wea = wea * corr + p0 * ea0 + p1 * ea1;
        m   = mn;
    }
    if (j < jend) {
        const int e  = eids[j];
        const int sj = srcarr[e];
        const float ea = edge_attr[(size_t)e * 16 + (c & 15)];
        const float kv = (float)qkvs[(size_t)sj * 1024 + 256 + tid];
        const float vv = (float)qkvs[(size_t)sj * 1024 + 512 + tid];
        float d = fmaf(qv, kv, qwv * ea);
#pragma unroll
        for (int off = 16; off; off >>= 1) d += __shfl_xor(d, off, 32);
        const float mn   = fmaxf(m, d);
        const float corr = __expf(m - mn);
        const float p    = __expf(d - mn);
        s   = s   * corr + p;
        acc = acc * corr + p * vv;
        wea = wea * corr + p * ea;
        m   = mn;
    }

    // ---- epilogue: ve = wea[h] @ We[:, tid]; msg = (acc + ve)/s ----
    if (c < 16) wea_s[h * 16 + c] = wea;
    __syncthreads();
    float ve = 0.f;
#pragma unroll
    for (int t = 0; t < 16; ++t)
        ve = fmaf(wea_s[h * 16 + t], Wel[t * DD + tid], ve);

    const float msg = (acc + ve) / (s + 1e-16f);
    const size_t o  = (size_t)i * DD + tid;
    x[o] += msg + (float)qkvs[(size_t)i * 1024 + 768 + tid];
}

// ---------------------------------------------------------------------------
// Launcher
// ---------------------------------------------------------------------------
extern "C" void kernel_launch(void* const* d_in, const int* in_sizes, int n_in,
                              void* d_out, int out_size, void* d_ws, size_t ws_size,
                              hipStream_t stream)
{
    const float* input = (const float*)d_in[0];
    const float* nemb  = (const float*)d_in[1];
    const float* eattr = (const float*)d_in[2];
    const int*   eidx  = (const int*)d_in[3];
    const float* Win   = (const float*)d_in[4];
    const float* b_in  = (const float*)d_in[5];
    const float* Wemb  = (const float*)d_in[6];
    const float* bemb  = (const float*)d_in[7];
    const float* Wfus  = (const float*)d_in[8];
    const float* bfus  = (const float*)d_in[9];
    const float* Wq    = (const float*)d_in[10];
    const float* bq    = (const float*)d_in[11];
    const float* Wk    = (const float*)d_in[12];
    const float* bk    = (const float*)d_in[13];
    const float* Wv    = (const float*)d_in[14];
    const float* bv    = (const float*)d_in[15];
    const float* We    = (const float*)d_in[16];
    const float* Wskip = (const float*)d_in[17];
    const float* bskip = (const float*)d_in[18];
    const float* n1g   = (const float*)d_in[19];
    const float* n1b   = (const float*)d_in[20];
    const float* W1f   = (const float*)d_in[21];
    const float* b1f   = (const float*)d_in[22];
    const float* W2f   = (const float*)d_in[23];
    const float* b2f   = (const float*)d_in[24];
    const float* n2g   = (const float*)d_in[25];
    const float* n2b   = (const float*)d_in[26];
    const float* fng   = (const float*)d_in[27];
    const float* fnb   = (const float*)d_in[28];

    const int* srcarr = eidx;
    const int* dstarr = eidx + EE;

    // -------- workspace layout (~113 MB) --------
    char* p = (char*)d_ws;
    auto alloc = [&](size_t bytes) { char* r = p; p += (bytes + 255) & ~(size_t)255; return r; };
    const size_t ND = (size_t)NN * DD;
    float* xA      = (float*)alloc(ND * 4);                 // f32 residual stream
    f16*   h_inp   = (f16*)alloc(ND * 2);
    f16*   h_emb   = (f16*)alloc(ND * 2);
    f16*   h_x     = (f16*)alloc(ND * 2);
    f16*   xn_h    = (f16*)alloc(ND * 2);
    f16*   qkvs_h  = (f16*)alloc((size_t)NN * 1024 * 2);    // also FFN mid (sequential use)
    f16*   mid_h   = qkvs_h;
    f16*   h_input = (f16*)alloc((size_t)NN * INDIM * 2);
    f16*   h_nemb  = (f16*)alloc((size_t)NN * INDIM * 2);
    f16*   Wt_in   = (f16*)alloc((size_t)INDIM * DD * 2);
    f16*   Wt_emb  = (f16*)alloc((size_t)INDIM * DD * 2);
    f16*   Wt_fus  = (f16*)alloc((size_t)768 * DD * 2);     // SINGLE layer (no L dim!)
    f16*   Wt_pack = (f16*)alloc((size_t)LLAY * DD * 1024 * 2);
    f16*   Wt_f1   = (f16*)alloc((size_t)LLAY * DD * DFFN * 2);
    f16*   Wt_f2   = (f16*)alloc((size_t)LLAY * DFFN * DD * 2);
    float* bpack   = (float*)alloc((size_t)LLAY * 1024 * 4);
    int*   cnt     = (int*)alloc(NN * 4);
    int*   cursor  = (int*)alloc(NN * 4);
    int*   row_ptr = (int*)alloc((NN + 1) * 4);
    int*   eids    = (int*)alloc(EE * 4);

    const int  lnGrid = (NN + 3) / 4;
    const dim3 gS(313, 2);   // Nout=256  (313*64 = 20032 rows)
    const dim3 gW(313, 8);   // Nout=1024

    // -------- weight & activation conversion --------
    hipMemsetAsync(cnt, 0, NN * sizeof(int), stream);
    cvtW_k<<<dim3(INDIM * DD / 256, 1), 256, 0, stream>>>(Win,  Wt_in,  INDIM, DD);
    cvtW_k<<<dim3(INDIM * DD / 256, 1), 256, 0, stream>>>(Wemb, Wt_emb, INDIM, DD);
    cvtW_k<<<dim3(768 * DD / 256,  1), 256, 0, stream>>>(Wfus, Wt_fus, 768, DD);   // grid.y=1: Wfus SHARED
    cvtW_k<<<dim3(DD * DFFN / 256, LLAY), 256, 0, stream>>>(W1f,  Wt_f1,  DD, DFFN);
    cvtW_k<<<dim3(DFFN * DD / 256, LLAY), 256, 0, stream>>>(W2f,  Wt_f2,  DFFN, DD);
    cvtW4_k<<<dim3(DD * 1024 / 256, LLAY), 256, 0, stream>>>(Wq, Wk, Wv, Wskip,
                                                             bq, bk, bv, bskip, Wt_pack, bpack);
    cvt_act_k<<<NN * INDIM / 4 / 256, 256, 0, stream>>>(input, h_input, NN * INDIM);
    cvt_act_k<<<NN * INDIM / 4 / 256, 256, 0, stream>>>(nemb,  h_nemb,  NN * INDIM);

    // input projections -> f16 [N,256]
    hgemm_k<3,false><<<gS, 256, 0, stream>>>(h_input, nullptr, nullptr, Wt_in,  b_in,
                                             nullptr, h_inp, nullptr, NN, INDIM, DD);
    hgemm_k<3,false><<<gS, 256, 0, stream>>>(h_nemb,  nullptr, nullptr, Wt_emb, bemb,
                                             nullptr, h_emb, nullptr, NN, INDIM, DD);
    // CSR build
    hist_k<<<EE / 256, 256, 0, stream>>>(dstarr, cnt);
    scan_k<<<1, 256, 0, stream>>>(cnt, row_ptr, cursor);
    scatter_k<<<EE / 256, 256, 0, stream>>>(dstarr, cursor, eids);

    for (int l = 0; l < LLAY; ++l) {
        const f16* hx_l = (l == 0) ? h_emb : h_x;

        // x = concat(x, inp_proj, emb_proj) @ Wfus + bfus -> xA (f32); Wt_fus shared
        hgemm_k<0,true><<<gS, 256, 0, stream>>>(hx_l, h_inp, h_emb,
            Wt_fus, bfus, xA, nullptr, nullptr, NN, 768, DD);
        // prenorm 1 -> f16
        ln_k<f16><<<lnGrid, 256, 0, stream>>>(xA, n1g + l * DD, n1b + l * DD, xn_h, NN);
        // q|k|v|skip in one GEMM -> f16 [N,1024]
        hgemm_k<3,false><<<gW, 256, 0, stream>>>(xn_h, nullptr, nullptr,
            Wt_pack + (size_t)l * DD * 1024, bpack + l * 1024, nullptr, qkvs_h, nullptr, NN, DD, 1024);
        // fused edge attention + skip + residual: xA += msg + skip
        edge_attn_k<<<NN, 256, 0, stream>>>(qkvs_h, eattr, We + (size_t)l * 16 * DD,
                                            row_ptr, eids, srcarr, xA);
        // prenorm 2 -> f16
        ln_k<f16><<<lnGrid, 256, 0, stream>>>(xA, n2g + l * DD, n2b + l * DD, xn_h, NN);
        // FFN: relu(xn @ W1f + b1f) -> f16 mid; xA += mid @ W2f + b2f (also emit h_x f16)
        hgemm_k<1,false><<<gW, 256, 0, stream>>>(xn_h, nullptr, nullptr,
            Wt_f1 + (size_t)l * DD * DFFN, b1f + l * DFFN, nullptr, mid_h, nullptr, NN, DD, DFFN);
        hgemm_k<2,false><<<gS, 256, 0, stream>>>(mid_h, nullptr, nullptr,
            Wt_f2 + (size_t)l * DFFN * DD, b2f + l * DD, xA, nullptr, h_x, NN, DFFN, DD);
    }

    // final LN -> d_out (f32)
    ln_k<float><<<lnGrid, 256, 0, stream>>>(xA, fng, fnb, (float*)d_out, NN);
}

// Round 13
// 1250.078 us; speedup vs baseline: 1.0330x; 1.0212x over previous
//
#include <hip/hip_runtime.h>
#include <math.h>

// Problem constants (from the reference file)
#define NN   20000
#define EE   320000
#define DD   256
#define HH   8
#define CC   32
#define DFFN 1024
#define LLAY 4
#define INDIM 64

typedef _Float16 f16;
typedef __attribute__((ext_vector_type(8))) _Float16 f16x8;
typedef __attribute__((ext_vector_type(4))) _Float16 f16x4;
typedef __attribute__((ext_vector_type(4))) float    f32x4;

// ---------------------------------------------------------------------------
// f16-MFMA GEMM [round-9 proven form — reg-staged, BM=64]:
//   out[M,Nout] = op( A[M,K](f16) @ W[K,Nout](chunked f16) + bias )
// BM=64, BN=128, BK=32; 256 thr = 4 waves in 2x2 grid; wave tile 32x64.
// W chunked: Wt[c][n][j] = W[c*8+j][n].
// MODE: 0 = f32 store | 1 = relu + f16 store | 2 = f32 residual add + f16 copy
//     | 3 = f16 store
// FUSED: A is concat [A0|A1|A2], each [M,256] f16 (K must be 768)
// ---------------------------------------------------------------------------
template<int MODE, bool FUSED>
__global__ __launch_bounds__(256)
void hgemm_k(const f16* __restrict__ A0, const f16* __restrict__ A1,
             const f16* __restrict__ A2, const f16* __restrict__ Wt,
             const float* __restrict__ bias, float* __restrict__ outF,
             f16* __restrict__ outH, f16* __restrict__ outH2,
             int M, int K, int Nout)
{
    __shared__ f16 Af[4 * 64 * 8];     // 4 KB
    __shared__ f16 Bf[4 * 128 * 8];    // 8 KB

    const int tid  = threadIdx.x;
    const int wid  = tid >> 6;
    const int lane = tid & 63;
    const int g    = lane >> 4;        // k-subchunk 0..3
    const int ln   = lane & 15;
    const int WR   = wid >> 1;         // wave row 0..1 (32 rows each)
    const int WC   = wid & 1;          // wave col 0..1 (64 cols each)
    const int bm   = blockIdx.x * 64;
    const int bn   = blockIdx.y * 128;

    f32x4 acc[2][4];
#pragma unroll
    for (int m = 0; m < 2; ++m)
#pragma unroll
        for (int n = 0; n < 4; ++n) acc[m][n] = (f32x4){0.f, 0.f, 0.f, 0.f};

    // A staging map: thread -> granule (c = tid&3, r = tid>>2)
    const int ar = tid >> 2;           // 0..63
    const int ac = tid & 3;            // 0..3

    for (int k0 = 0; k0 < K; k0 += 32) {
        // ---- A granule: A[bm+ar][k0+8*ac .. +7] ----
        f16x8 av = {};
        {
            const int grow = bm + ar;
            if (grow < M) {
                const f16* gsrc;
                if (FUSED) {
                    const int kg  = k0 + ac * 8;
                    const int sel = kg >> 8;
                    const f16* Asrc = (sel == 0) ? A0 : ((sel == 1) ? A1 : A2);
                    gsrc = Asrc + (size_t)grow * 256 + (kg & 255);
                } else {
                    gsrc = A0 + (size_t)grow * K + k0 + ac * 8;
                }
                av = *(const f16x8*)gsrc;
            }
        }
        // ---- B granules (2/thread): granule (c = s>>7, col = s&127) ----
        f16x8 bv0, bv1;
        {
            const int s0 = tid;              // c = tid>>7 (0..1), col = tid&127
            const int s1 = tid + 256;        // c = 2..3
            bv0 = *(const f16x8*)(Wt + ((size_t)((k0 >> 3) + (s0 >> 7)) * Nout + bn + (s0 & 127)) * 8);
            bv1 = *(const f16x8*)(Wt + ((size_t)((k0 >> 3) + (s1 >> 7)) * Nout + bn + (s1 & 127)) * 8);
        }

        __syncthreads();                     // previous iter's reads done
        *(f16x8*)&Af[(ac * 64 + ar) * 8] = av;
        *(f16x8*)&Bf[(size_t)tid * 8]         = bv0;
        *(f16x8*)&Bf[(size_t)(tid + 256) * 8] = bv1;
        __syncthreads();                     // tiles visible

        f16x8 af[2], bf[4];
#pragma unroll
        for (int m = 0; m < 2; ++m)
            af[m] = *(const f16x8*)&Af[(g * 64 + WR * 32 + m * 16 + ln) * 8];
#pragma unroll
        for (int n = 0; n < 4; ++n)
            bf[n] = *(const f16x8*)&Bf[(g * 128 + WC * 64 + n * 16 + ln) * 8];
#pragma unroll
        for (int m = 0; m < 2; ++m)
#pragma unroll
            for (int n = 0; n < 4; ++n)
                acc[m][n] = __builtin_amdgcn_mfma_f32_16x16x32_f16(af[m], bf[n], acc[m][n], 0, 0, 0);
    }

    // ---- epilogue: C/D map col=ln, row=g*4+reg per 16x16 fragment ----
    float bvv[4];
#pragma unroll
    for (int n = 0; n < 4; ++n) bvv[n] = bias[bn + WC * 64 + n * 16 + ln];

#pragma unroll
    for (int m = 0; m < 2; ++m) {
        const int rbase = bm + WR * 32 + m * 16 + g * 4;
#pragma unroll
        for (int reg = 0; reg < 4; ++reg) {
            const int row = rbase + reg;
            if (row >= M) continue;
#pragma unroll
            for (int n = 0; n < 4; ++n) {
                const int col = bn + WC * 64 + n * 16 + ln;
                float v = acc[m][n][reg] + bvv[n];
                const size_t idx = (size_t)row * Nout + col;
                if (MODE == 0) {
                    outF[idx] = v;
                } else if (MODE == 1) {
                    outH[idx] = (f16)fmaxf(v, 0.f);
                } else if (MODE == 2) {
                    const float nv = outF[idx] + v;
                    outF[idx] = nv;
                    outH2[idx] = (f16)nv;
                } else {
                    outH[idx] = (f16)v;
                }
            }
        }
    }
}

// ---------------------------------------------------------------------------
// Weight conversion: W [K,N] f32 -> Wt chunked f16 [K/8][N][8]; grid.y = layer
// (grid.y MUST be 1 for unstacked weights — Wfus is [768,256] with NO L dim;
//  the round-4/5 crash was a 2.25MB OOB read from grid.y=LLAY on Wfus).
// ---------------------------------------------------------------------------
__global__ __launch_bounds__(256)
void cvtW_k(const float* __restrict__ W, f16* __restrict__ Wt, int K, int N)
{
    const size_t lo  = (size_t)blockIdx.y * K * N;
    const int    idx = blockIdx.x * 256 + threadIdx.x;   // over K*N
    const int    k   = idx / N;
    const int    n   = idx - k * N;
    Wt[lo + ((size_t)(k >> 3) * N + n) * 8 + (k & 7)] = (f16)W[lo + idx];
}

// Pack Wq|Wk|Wv|Wskip ([L,256,256] each) into chunked f16 [32][1024][8] per
// layer + f32 bias [1024]. grid.y = layer.
__global__ __launch_bounds__(256)
void cvtW4_k(const float* __restrict__ Wq, const float* __restrict__ Wk,
             const float* __restrict__ Wv, const float* __restrict__ Ws,
             const float* __restrict__ bq, const float* __restrict__ bk,
             const float* __restrict__ bv, const float* __restrict__ bs,
             f16* __restrict__ Wt, float* __restrict__ bout)
{
    const int l   = blockIdx.y;
    const int idx = blockIdx.x * 256 + threadIdx.x;   // over 256*1024
    const int k   = idx >> 10;
    const int n   = idx & 1023;
    const int m   = n >> 8;          // 0=q 1=k 2=v 3=skip
    const int c   = n & 255;
    const float* src = (m == 0) ? Wq : (m == 1) ? Wk : (m == 2) ? Wv : Ws;
    const float  v   = src[(size_t)l * 65536 + k * 256 + c];
    Wt[(size_t)l * 262144 + ((size_t)(k >> 3) * 1024 + n) * 8 + (k & 7)] = (f16)v;
    if (k == 0) {
        const float* bsrc = (m == 0) ? bq : (m == 1) ? bk : (m == 2) ? bv : bs;
        bout[l * 1024 + n] = bsrc[l * 256 + c];
    }
}

// Elementwise f32 -> f16. n multiple of 4.
__global__ __launch_bounds__(256)
void cvt_act_k(const float* __restrict__ in, f16* __restrict__ out, int n)
{
    const int i = (blockIdx.x * 256 + threadIdx.x) * 4;
    if (i < n) {
        const float4 v = *(const float4*)&in[i];
        f16x4 o = {(f16)v.x, (f16)v.y, (f16)v.z, (f16)v.w};
        *(f16x4*)&out[i] = o;
    }
}

// ---------------------------------------------------------------------------
// LayerNorm over D=256, f32 in, f16 or f32 out. One wave per row.
// ---------------------------------------------------------------------------
template<typename T>
__global__ __launch_bounds__(256)
void ln_k(const float* __restrict__ in, const float* __restrict__ g,
          const float* __restrict__ b, T* __restrict__ out, int M)
{
    const int wave = threadIdx.x >> 6;
    const int lane = threadIdx.x & 63;
    const int row  = blockIdx.x * 4 + wave;
    if (row >= M) return;

    const float4 v = *(const float4*)&in[(size_t)row * DD + lane * 4];
    float s = v.x + v.y + v.z + v.w;
#pragma unroll
    for (int off = 32; off; off >>= 1) s += __shfl_xor(s, off, 64);
    const float mu = s * (1.f / 256.f);

    const float dx = v.x - mu, dy = v.y - mu, dz = v.z - mu, dw = v.w - mu;
    float q = dx*dx + dy*dy + dz*dz + dw*dw;
#pragma unroll
    for (int off = 32; off; off >>= 1) q += __shfl_xor(q, off, 64);
    const float rs = rsqrtf(q * (1.f / 256.f) + 1e-5f);

    const float4 gv = *(const float4*)&g[lane * 4];
    const float4 bv = *(const float4*)&b[lane * 4];
    const float ox = dx * rs * gv.x + bv.x;
    const float oy = dy * rs * gv.y + bv.y;
    const float oz = dz * rs * gv.z + bv.z;
    const float ow = dw * rs * gv.w + bv.w;
    if constexpr (sizeof(T) == 2) {
        f16x4 o = {(f16)ox, (f16)oy, (f16)oz, (f16)ow};
        *(f16x4*)&out[(size_t)row * DD + lane * 4] = o;
    } else {
        float4 o = {ox, oy, oz, ow};
        *(float4*)&out[(size_t)row * DD + lane * 4] = o;
    }
}

// ---------------------------------------------------------------------------
// CSR build [round-3 proven]
// ---------------------------------------------------------------------------
__global__ void hist_k(const int* __restrict__ dst, int* __restrict__ cnt)
{
    const int e = blockIdx.x * blockDim.x + threadIdx.x;
    if (e < EE) atomicAdd(&cnt[dst[e]], 1);
}

__global__ __launch_bounds__(256)
void scan_k(const int* __restrict__ cnt, int* __restrict__ row_ptr,
            int* __restrict__ cursor)
{
    __shared__ int sums[256];
    const int t  = threadIdx.x;
    const int CH = (NN + 255) / 256;       // 79
    const int s0 = t * CH;
    const int s1 = min(s0 + CH, NN);

    int s = 0;
    for (int i = s0; i < s1; ++i) s += cnt[i];
    sums[t] = s;
    __syncthreads();
    for (int off = 1; off < 256; off <<= 1) {
        const int v = (t >= off) ? sums[t - off] : 0;
        __syncthreads();
        sums[t] += v;
        __syncthreads();
    }
    int run = (t == 0) ? 0 : sums[t - 1];
    for (int i = s0; i < s1; ++i) {
        row_ptr[i] = run;
        cursor[i]  = run;
        run += cnt[i];
    }
    if (t == 255) row_ptr[NN] = run;       // == EE
}

__global__ void scatter_k(const int* __restrict__ dst, int* __restrict__ cursor,
                          int* __restrict__ eids)
{
    const int e = blockIdx.x * blockDim.x + threadIdx.x;
    if (e < EE) {
        const int idx = atomicAdd(&cursor[dst[e]], 1);
        eids[idx] = e;
    }
}

// ---------------------------------------------------------------------------
// Fused edge attention [round-12 algebraic form + 4-EDGE UNROLL]:
//   score: q·(k+e) = q·k + ea·qwe (qwe precomputed once per dst into LDS)
//   value: Σ_j p_j·e_j = (Σ_j p_j·ea_j) @ We (wea accumulated online)
// Round-12 PMC: VALUBusy 41%, HBM 1.5 TB/s, occ 80% -> LATENCY-bound on the
// dependent chain eids -> srcarr -> 512B k/v gather. 4 edges/iter doubles
// the in-flight gathers on that chain (3 dependent load rounds per 4 edges
// instead of per 2). qkvs f16 [N,1024] = [q|k|v|skip]. One block per dst;
// channel = tid; online softmax per 32-lane head. x[i] += msg + skip[i].
// ---------------------------------------------------------------------------
__global__ __launch_bounds__(256)
void edge_attn_k(const f16* __restrict__ qkvs, const float* __restrict__ edge_attr,
                 const float* __restrict__ Wel, const int* __restrict__ row_ptr,
                 const int* __restrict__ eids, const int* __restrict__ srcarr,
                 float* __restrict__ x)
{
    __shared__ float qwe[128];     // [h][t]
    __shared__ float wea_s[128];   // [h][t]

    const int i   = blockIdx.x;
    const int tid = threadIdx.x;
    const int h   = tid >> 5;      // head 0..7
    const int c   = tid & 31;      // channel within head

    // ---- one-time: qwe[h][t] = (q_h/√32) · We[t, h-block] ----
    if (tid < 128) {
        const int hh = tid >> 4, tt = tid & 15;
        const f16*   qrow = qkvs + (size_t)i * 1024 + hh * 32;
        const float* wrow = Wel + tt * 256 + hh * 32;
        const f16x8* q8 = (const f16x8*)qrow;        // 64B-aligned
        float a0 = 0.f;
#pragma unroll
        for (int b = 0; b < 4; ++b) {
            const f16x8 qq = q8[b];
#pragma unroll
            for (int u = 0; u < 8; ++u)
                a0 = fmaf((float)qq[u], wrow[b * 8 + u], a0);
        }
        qwe[tid] = a0 * 0.17677669529663687f;        // 1/sqrt(32)
    }
    const float qv = (float)qkvs[(size_t)i * 1024 + tid] * 0.17677669529663687f;
    __syncthreads();

    const float qwv = (c < 16) ? qwe[h * 16 + c] : 0.f;   // per-thread constant

    float m = -INFINITY, s = 0.f, acc = 0.f, wea = 0.f;
    const int jbeg = row_ptr[i];
    const int jend = row_ptr[i + 1];

    int j = jbeg;
    // ---- 4-edge unrolled main loop (2x MLP on the gather chain) ----
    for (; j + 3 < jend; j += 4) {
        const int e0 = eids[j],     e1 = eids[j + 1];
        const int e2 = eids[j + 2], e3 = eids[j + 3];
        const int s0 = srcarr[e0],  s1 = srcarr[e1];
        const int s2 = srcarr[e2],  s3 = srcarr[e3];

        const float ea0 = edge_attr[(size_t)e0 * 16 + (c & 15)];
        const float ea1 = edge_attr[(size_t)e1 * 16 + (c & 15)];
        const float ea2 = edge_attr[(size_t)e2 * 16 + (c & 15)];
        const float ea3 = edge_attr[(size_t)e3 * 16 + (c & 15)];
        const float kv0 = (float)qkvs[(size_t)s0 * 1024 + 256 + tid];
        const float kv1 = (float)qkvs[(size_t)s1 * 1024 + 256 + tid];
        const float kv2 = (float)qkvs[(size_t)s2 * 1024 + 256 + tid];
        const float kv3 = (float)qkvs[(size_t)s3 * 1024 + 256 + tid];
        const float vv0 = (float)qkvs[(size_t)s0 * 1024 + 512 + tid];
        const float vv1 = (float)qkvs[(size_t)s1 * 1024 + 512 + tid];
        const float vv2 = (float)qkvs[(size_t)s2 * 1024 + 512 + tid];
        const float vv3 = (float)qkvs[(size_t)s3 * 1024 + 512 + tid];

        float d0 = fmaf(qv, kv0, qwv * ea0);   // lanes c>=16: qwv=0
        float d1 = fmaf(qv, kv1, qwv * ea1);
        float d2 = fmaf(qv, kv2, qwv * ea2);
        float d3 = fmaf(qv, kv3, qwv * ea3);
#pragma unroll
        for (int off = 16; off; off >>= 1) {
            d0 += __shfl_xor(d0, off, 32);
            d1 += __shfl_xor(d1, off, 32);
            d2 += __shfl_xor(d2, off, 32);
            d3 += __shfl_xor(d3, off, 32);
        }

        const float mn   = fmaxf(fmaxf(m, fmaxf(d0, d1)), fmaxf(d2, d3));
        const float corr = __expf(m - mn);     // exp(-inf)=0 handles first iter
        const float p0   = __expf(d0 - mn);
        const float p1   = __expf(d1 - mn);
        const float p2   = __expf(d2 - mn);
        const float p3   = __expf(d3 - mn);
        s   = s   * corr + (p0 + p1) + (p2 + p3);
        acc = acc * corr + (p0 * vv0 + p1 * vv1) + (p2 * vv2 + p3 * vv3);
        wea = wea * corr + (p0 * ea0 + p1 * ea1) + (p2 * ea2 + p3 * ea3);
        m   = mn;
    }
    // ---- tail (0..3 edges) ----
    for (; j < jend; ++j) {
        const int e  = eids[j];
        const int sj = srcarr[e];
        const float ea = edge_attr[(size_t)e * 16 + (c & 15)];
        const float kv = (float)qkvs[(size_t)sj * 1024 + 256 + tid];
        const float vv = (float)qkvs[(size_t)sj * 1024 + 512 + tid];
        float d = fmaf(qv, kv, qwv * ea);
#pragma unroll
        for (int off = 16; off; off >>= 1) d += __shfl_xor(d, off, 32);
        const float mn   = fmaxf(m, d);
        const float corr = __expf(m - mn);
        const float p    = __expf(d - mn);
        s   = s   * corr + p;
        acc = acc * corr + p * vv;
        wea = wea * corr + p * ea;
        m   = mn;
    }

    // ---- epilogue: ve = wea[h] @ We[:, tid]; msg = (acc + ve)/s ----
    if (c < 16) wea_s[h * 16 + c] = wea;
    __syncthreads();
    float ve = 0.f;
#pragma unroll
    for (int t = 0; t < 16; ++t)
        ve = fmaf(wea_s[h * 16 + t], Wel[t * DD + tid], ve);

    const float msg = (acc + ve) / (s + 1e-16f);
    const size_t o  = (size_t)i * DD + tid;
    x[o] += msg + (float)qkvs[(size_t)i * 1024 + 768 + tid];
}

// ---------------------------------------------------------------------------
// Launcher
// ---------------------------------------------------------------------------
extern "C" void kernel_launch(void* const* d_in, const int* in_sizes, int n_in,
                              void* d_out, int out_size, void* d_ws, size_t ws_size,
                              hipStream_t stream)
{
    const float* input = (const float*)d_in[0];
    const float* nemb  = (const float*)d_in[1];
    const float* eattr = (const float*)d_in[2];
    const int*   eidx  = (const int*)d_in[3];
    const float* Win   = (const float*)d_in[4];
    const float* b_in  = (const float*)d_in[5];
    const float* Wemb  = (const float*)d_in[6];
    const float* bemb  = (const float*)d_in[7];
    const float* Wfus  = (const float*)d_in[8];
    const float* bfus  = (const float*)d_in[9];
    const float* Wq    = (const float*)d_in[10];
    const float* bq    = (const float*)d_in[11];
    const float* Wk    = (const float*)d_in[12];
    const float* bk    = (const float*)d_in[13];
    const float* Wv    = (const float*)d_in[14];
    const float* bv    = (const float*)d_in[15];
    const float* We    = (const float*)d_in[16];
    const float* Wskip = (const float*)d_in[17];
    const float* bskip = (const float*)d_in[18];
    const float* n1g   = (const float*)d_in[19];
    const float* n1b   = (const float*)d_in[20];
    const float* W1f   = (const float*)d_in[21];
    const float* b1f   = (const float*)d_in[22];
    const float* W2f   = (const float*)d_in[23];
    const float* b2f   = (const float*)d_in[24];
    const float* n2g   = (const float*)d_in[25];
    const float* n2b   = (const float*)d_in[26];
    const float* fng   = (const float*)d_in[27];
    const float* fnb   = (const float*)d_in[28];

    const int* srcarr = eidx;
    const int* dstarr = eidx + EE;

    // -------- workspace layout (~113 MB) --------
    char* p = (char*)d_ws;
    auto alloc = [&](size_t bytes) { char* r = p; p += (bytes + 255) & ~(size_t)255; return r; };
    const size_t ND = (size_t)NN * DD;
    float* xA      = (float*)alloc(ND * 4);                 // f32 residual stream
    f16*   h_inp   = (f16*)alloc(ND * 2);
    f16*   h_emb   = (f16*)alloc(ND * 2);
    f16*   h_x     = (f16*)alloc(ND * 2);
    f16*   xn_h    = (f16*)alloc(ND * 2);
    f16*   qkvs_h  = (f16*)alloc((size_t)NN * 1024 * 2);    // also FFN mid (sequential use)
    f16*   mid_h   = qkvs_h;
    f16*   h_input = (f16*)alloc((size_t)NN * INDIM * 2);
    f16*   h_nemb  = (f16*)alloc((size_t)NN * INDIM * 2);
    f16*   Wt_in   = (f16*)alloc((size_t)INDIM * DD * 2);
    f16*   Wt_emb  = (f16*)alloc((size_t)INDIM * DD * 2);
    f16*   Wt_fus  = (f16*)alloc((size_t)768 * DD * 2);     // SINGLE layer (no L dim!)
    f16*   Wt_pack = (f16*)alloc((size_t)LLAY * DD * 1024 * 2);
    f16*   Wt_f1   = (f16*)alloc((size_t)LLAY * DD * DFFN * 2);
    f16*   Wt_f2   = (f16*)alloc((size_t)LLAY * DFFN * DD * 2);
    float* bpack   = (float*)alloc((size_t)LLAY * 1024 * 4);
    int*   cnt     = (int*)alloc(NN * 4);
    int*   cursor  = (int*)alloc(NN * 4);
    int*   row_ptr = (int*)alloc((NN + 1) * 4);
    int*   eids    = (int*)alloc(EE * 4);

    const int  lnGrid = (NN + 3) / 4;
    const dim3 gS(313, 2);   // Nout=256  (313*64 = 20032 rows)
    const dim3 gW(313, 8);   // Nout=1024

    // -------- weight & activation conversion --------
    hipMemsetAsync(cnt, 0, NN * sizeof(int), stream);
    cvtW_k<<<dim3(INDIM * DD / 256, 1), 256, 0, stream>>>(Win,  Wt_in,  INDIM, DD);
    cvtW_k<<<dim3(INDIM * DD / 256, 1), 256, 0, stream>>>(Wemb, Wt_emb, INDIM, DD);
    cvtW_k<<<dim3(768 * DD / 256,  1), 256, 0, stream>>>(Wfus, Wt_fus, 768, DD);   // grid.y=1: Wfus SHARED
    cvtW_k<<<dim3(DD * DFFN / 256, LLAY), 256, 0, stream>>>(W1f,  Wt_f1,  DD, DFFN);
    cvtW_k<<<dim3(DFFN * DD / 256, LLAY), 256, 0, stream>>>(W2f,  Wt_f2,  DFFN, DD);
    cvtW4_k<<<dim3(DD * 1024 / 256, LLAY), 256, 0, stream>>>(Wq, Wk, Wv, Wskip,
                                                             bq, bk, bv, bskip, Wt_pack, bpack);
    cvt_act_k<<<NN * INDIM / 4 / 256, 256, 0, stream>>>(input, h_input, NN * INDIM);
    cvt_act_k<<<NN * INDIM / 4 / 256, 256, 0, stream>>>(nemb,  h_nemb,  NN * INDIM);

    // input projections -> f16 [N,256]
    hgemm_k<3,false><<<gS, 256, 0, stream>>>(h_input, nullptr, nullptr, Wt_in,  b_in,
                                             nullptr, h_inp, nullptr, NN, INDIM, DD);
    hgemm_k<3,false><<<gS, 256, 0, stream>>>(h_nemb,  nullptr, nullptr, Wt_emb, bemb,
                                             nullptr, h_emb, nullptr, NN, INDIM, DD);
    // CSR build
    hist_k<<<EE / 256, 256, 0, stream>>>(dstarr, cnt);
    scan_k<<<1, 256, 0, stream>>>(cnt, row_ptr, cursor);
    scatter_k<<<EE / 256, 256, 0, stream>>>(dstarr, cursor, eids);

    for (int l = 0; l < LLAY; ++l) {
        const f16* hx_l = (l == 0) ? h_emb : h_x;

        // x = concat(x, inp_proj, emb_proj) @ Wfus + bfus -> xA (f32); Wt_fus shared
        hgemm_k<0,true><<<gS, 256, 0, stream>>>(hx_l, h_inp, h_emb,
            Wt_fus, bfus, xA, nullptr, nullptr, NN, 768, DD);
        // prenorm 1 -> f16
        ln_k<f16><<<lnGrid, 256, 0, stream>>>(xA, n1g + l * DD, n1b + l * DD, xn_h, NN);
        // q|k|v|skip in one GEMM -> f16 [N,1024]
        hgemm_k<3,false><<<gW, 256, 0, stream>>>(xn_h, nullptr, nullptr,
            Wt_pack + (size_t)l * DD * 1024, bpack + l * 1024, nullptr, qkvs_h, nullptr, NN, DD, 1024);
        // fused edge attention + skip + residual: xA += msg + skip
        edge_attn_k<<<NN, 256, 0, stream>>>(qkvs_h, eattr, We + (size_t)l * 16 * DD,
                                            row_ptr, eids, srcarr, xA);
        // prenorm 2 -> f16
        ln_k<f16><<<lnGrid, 256, 0, stream>>>(xA, n2g + l * DD, n2b + l * DD, xn_h, NN);
        // FFN: relu(xn @ W1f + b1f) -> f16 mid; xA += mid @ W2f + b2f (also emit h_x f16)
        hgemm_k<1,false><<<gW, 256, 0, stream>>>(xn_h, nullptr, nullptr,
            Wt_f1 + (size_t)l * DD * DFFN, b1f + l * DFFN, nullptr, mid_h, nullptr, NN, DD, DFFN);
        hgemm_k<2,false><<<gS, 256, 0, stream>>>(mid_h, nullptr, nullptr,
            Wt_f2 + (size_t)l * DFFN * DD, b2f + l * DD, xA, nullptr, h_x, NN, DFFN, DD);
    }

    // final LN -> d_out (f32)
    ln_k<float><<<lnGrid, 256, 0, stream>>>(xA, fng, fnb, (float*)d_out, NN);
}